// Round 3
// baseline (217.335 us; speedup 1.0000x reference)
//
#include <hip/hip_runtime.h>
#include <cstdint>

typedef short short8 __attribute__((ext_vector_type(8)));
typedef short short4_t __attribute__((ext_vector_type(4)));
typedef float floatx4 __attribute__((ext_vector_type(4)));

#define MFMA_BF16 __builtin_amdgcn_mfma_f32_16x16x32_bf16

// round-to-nearest-even fp32 -> bf16 (bits in a short)
__device__ __forceinline__ short f2bf(float f) {
  union { float f; unsigned u; } a; a.f = f;
  unsigned r = a.u + 0x7FFFu + ((a.u >> 16) & 1u);
  return (short)(r >> 16);
}
__device__ __forceinline__ float bf2f(short s) {
  union { unsigned u; float f; } a;
  a.u = ((unsigned)(unsigned short)s) << 16;
  return a.f;
}
__device__ __forceinline__ float silu_f(float v) {
  return v / (1.0f + __expf(-v));
}

#define QDIM 256
#define DEMB 64
#define TILE_T 32
#define ITERS 4          // tokens per block = 128
#define NBLK1 512
#define YSTR 264         // shorts; 528 B rows (16B aligned)
#define TSTR 40          // UVT t-stride in shorts; 80 B rows (16B aligned, conflict-free)
#define HSTR 72          // shorts; 144 B rows

// output layout (floats)
#define OFF_QKV 4194304
#define OFF_SW  4243456
#define OFF_WO  4276224

// ws layout (floats): [0, 32768) ao partial copies; [32768,32774) sums;
// [32774] counter; byte 131104: aoT bf16 [64 e][64 d]
#define AO_COPIES 8
#define WS_SUMS   32768
#define WS_AOT    32776

// k1 shared memory carve (bytes)
#define SM_Y   0                       // 32*264*2 = 16896
#define SM_UVT 16896                   // 128*40*2 = 10240
#define SM_H   27136                   // 32*72*2  = 4608
#define SM_TOT 31744
// finalize overlay (after main loop):
#define SM_AOFT 0                      // 64*65*4 = 16640
#define SM_SSP  16640                  // 256*4
#define SM_SCR  17664                  // 64*4

// ============================ K1: streaming ============================
__global__ __launch_bounds__(256, 2) void k1_main(
    const float* __restrict__ x, const float* __restrict__ y,
    const float* __restrict__ w_sw, const float* __restrict__ w_out,
    float* __restrict__ y_out, float* __restrict__ ao_copies,
    unsigned int* __restrict__ counter, unsigned short* __restrict__ aoT)
{
  __shared__ __align__(16) char smem[SM_TOT];
  short* Ylds = (short*)(smem + SM_Y);
  short* UVT  = (short*)(smem + SM_UVT);
  short* Hlds = (short*)(smem + SM_H);

  const int tid  = threadIdx.x;
  const int lane = tid & 63;
  const int wave = tid >> 6;
  const int l15  = lane & 15;
  const int quad = lane >> 4;
  const floatx4 fzero = {0.f, 0.f, 0.f, 0.f};
  const int tok0 = blockIdx.x * (TILE_T * ITERS);

  // ---- issue tile-0 y prefetch first (longest latency) ----
  float4 yreg[8];
  {
    const float4* src = (const float4*)(y + (size_t)tok0 * QDIM);
#pragma unroll
    for (int rep = 0; rep < 8; ++rep) yreg[rep] = src[tid + rep * 256];
  }

  // ---- register-resident B fragments ----
  short8 b1[2][8];
#pragma unroll
  for (int nt = 0; nt < 2; ++nt) {
    const float* wr = w_sw + (size_t)(wave * 32 + nt * 16 + l15) * QDIM;
#pragma unroll
    for (int kt = 0; kt < 8; ++kt) {
      const float* p = wr + kt * 32 + quad * 8;
      short8 f;
#pragma unroll
      for (int j = 0; j < 8; ++j) f[j] = f2bf(p[j]);
      b1[nt][kt] = f;
    }
  }
  short8 b2[2];
  {
    const float* wr = w_out + (size_t)(wave * 16 + l15) * DEMB;
#pragma unroll
    for (int kt = 0; kt < 2; ++kt) {
      const float* p = wr + kt * 32 + quad * 8;
      short8 f;
#pragma unroll
      for (int j = 0; j < 8; ++j) f[j] = f2bf(p[j]);
      b2[kt] = f;
    }
  }

  floatx4 ao_acc[4];
#pragma unroll
  for (int i = 0; i < 4; ++i) ao_acc[i] = fzero;

  float xreg[8];

  for (int it = 0; it < ITERS; ++it) {
    const int tbase = tok0 + it * TILE_T;

    // ---- stage prefetched y -> bf16 Ylds (b64 stores) ----
#pragma unroll
    for (int rep = 0; rep < 8; ++rep) {
      int i = tid + rep * 256;
      int tok = i >> 6;
      int col = (i & 63) * 4;
      float4 f = yreg[rep];
      short4_t p4 = { f2bf(f.x), f2bf(f.y), f2bf(f.z), f2bf(f.w) };
      *(short4_t*)&Ylds[tok * YSTR + col] = p4;
    }

    // ---- prefetch next y tile ----
    if (it + 1 < ITERS) {
      const float4* src = (const float4*)(y + (size_t)(tbase + TILE_T) * QDIM);
#pragma unroll
      for (int rep = 0; rep < 8; ++rep) yreg[rep] = src[tid + rep * 256];
    }
    // ---- prefetch x for THIS tile (MFMA D layout; used at epilogue) ----
    {
      const float* xb = x + (size_t)tbase * DEMB + wave * 16 + l15;
#pragma unroll
      for (int mt = 0; mt < 2; ++mt)
#pragma unroll
        for (int r = 0; r < 4; ++r)
          xreg[mt * 4 + r] = xb[(mt * 16 + quad * 4 + r) * DEMB];
    }
    __syncthreads();

    // ---- UV = Ytile @ Wsw^T ----
    floatx4 acc[2][2];
#pragma unroll
    for (int a = 0; a < 2; ++a)
#pragma unroll
      for (int b = 0; b < 2; ++b) acc[a][b] = fzero;
#pragma unroll
    for (int kt = 0; kt < 8; ++kt) {
      short8 a0 = *(const short8*)&Ylds[(l15)      * YSTR + kt * 32 + quad * 8];
      short8 a1 = *(const short8*)&Ylds[(16 + l15) * YSTR + kt * 32 + quad * 8];
      acc[0][0] = MFMA_BF16(a0, b1[0][kt], acc[0][0], 0, 0, 0);
      acc[0][1] = MFMA_BF16(a0, b1[1][kt], acc[0][1], 0, 0, 0);
      acc[1][0] = MFMA_BF16(a1, b1[0][kt], acc[1][0], 0, 0, 0);
      acc[1][1] = MFMA_BF16(a1, b1[1][kt], acc[1][1], 0, 0, 0);
    }
    // ---- writeback as bf16 UV^T[c][t]: packed b64 (4 consecutive t) ----
#pragma unroll
    for (int mt = 0; mt < 2; ++mt)
#pragma unroll
      for (int nt = 0; nt < 2; ++nt) {
        short4_t p4;
#pragma unroll
        for (int r = 0; r < 4; ++r) p4[r] = f2bf(acc[mt][nt][r]);
        int c  = wave * 32 + nt * 16 + l15;
        int t0 = mt * 16 + quad * 4;
        *(short4_t*)&UVT[c * TSTR + t0] = p4;
      }
    __syncthreads();

    // ---- h = u * silu(v): thread = (d = tid&63, t0 = (tid>>6)*8) ----
    {
      int d  = tid & 63;
      int t0 = (tid >> 6) * 8;
      short8 u8 = *(const short8*)&UVT[d * TSTR + t0];
      short8 v8 = *(const short8*)&UVT[(64 + d) * TSTR + t0];
#pragma unroll
      for (int j = 0; j < 8; ++j) {
        float h = bf2f(u8[j]) * silu_f(bf2f(v8[j]));
        Hlds[(t0 + j) * HSTR + d] = f2bf(h);
      }
    }
    // ---- ao += u^T v (all-b128 fragment reads) ----
    {
      short8 a3 = *(const short8*)&UVT[(wave * 16 + l15) * TSTR + quad * 8];
#pragma unroll
      for (int et = 0; et < 4; ++et) {
        short8 b3 = *(const short8*)&UVT[(64 + et * 16 + l15) * TSTR + quad * 8];
        ao_acc[et] = MFMA_BF16(a3, b3, ao_acc[et], 0, 0, 0);
      }
    }
    __syncthreads();

    // ---- y_out = x + H @ Wout^T ----
#pragma unroll
    for (int mt = 0; mt < 2; ++mt) {
      floatx4 acc2 = fzero;
#pragma unroll
      for (int kt = 0; kt < 2; ++kt) {
        short8 a2 = *(const short8*)&Hlds[(mt * 16 + l15) * HSTR + kt * 32 + quad * 8];
        acc2 = MFMA_BF16(a2, b2[kt], acc2, 0, 0, 0);
      }
      int e = wave * 16 + l15;
#pragma unroll
      for (int r = 0; r < 4; ++r) {
        size_t idx = (size_t)(tbase + mt * 16 + quad * 4 + r) * DEMB + e;
        y_out[idx] = xreg[mt * 4 + r] + acc2[r];
      }
    }
    // no 4th sync: next stage writes Ylds (last read 2 barriers ago),
    // next UVT write is behind the next stage barrier.
  }

  // ---- flush ao partials ----
  float* dst = ao_copies + (blockIdx.x & (AO_COPIES - 1)) * 4096;
#pragma unroll
  for (int et = 0; et < 4; ++et)
#pragma unroll
    for (int r = 0; r < 4; ++r) {
      int d = wave * 16 + quad * 4 + r;
      int e = et * 16 + l15;
      atomicAdd(&dst[d * 64 + e], ao_acc[et][r]);
    }

  // ---- last block finalizes ao -> bf16 aoT (release/acquire via counter) ----
  __threadfence();
  __syncthreads();
  __shared__ int lastFlag;
  if (tid == 0) lastFlag = (atomicAdd(counter, 1u) == NBLK1 - 1) ? 1 : 0;
  __syncthreads();
  if (!lastFlag) return;
  __threadfence();   // acquire: see all blocks' ao_copies atomics

  float* aoFT = (float*)(smem + SM_AOFT);   // [e][d], pad 65
  float* ssP  = (float*)(smem + SM_SSP);
  float* scR  = (float*)(smem + SM_SCR);

#pragma unroll
  for (int k = 0; k < 16; ++k) {
    int idx = k * 256 + tid;          // = d*64 + e, coalesced
    float v = 0.f;
#pragma unroll
    for (int c = 0; c < AO_COPIES; ++c) v += ao_copies[c * 4096 + idx];
    v *= (1.0f / 64.0f);              // /B * n_embd^-0.5
    int d = idx >> 6, e = idx & 63;
    aoFT[e * 65 + d] = v;
  }
  __syncthreads();
  {
    int d = tid >> 2, q = tid & 3;
    float ssp = 0.f;
#pragma unroll
    for (int e2 = 0; e2 < 16; ++e2) {
      float v = aoFT[(q * 16 + e2) * 65 + d];
      ssp += v * v;
    }
    ssP[tid] = ssp;
  }
  __syncthreads();
  if (tid < 64) {
    float ss = ssP[tid * 4] + ssP[tid * 4 + 1] + ssP[tid * 4 + 2] + ssP[tid * 4 + 3];
    scR[tid] = rsqrtf(ss * (1.0f / 64.0f) + 1.1920929e-07f);
  }
  __syncthreads();
#pragma unroll
  for (int k = 0; k < 16; ++k) {
    int j = k * 256 + tid;            // = e*64 + d
    int e = j >> 6, d = j & 63;
    aoT[j] = (unsigned short)f2bf(aoFT[e * 65 + d] * scR[d]);
  }
}

// ============ K3: weight-update candidates via MFMA (84 waves) =========
__global__ __launch_bounds__(64) void k3_updates(
    const float* __restrict__ w_qkv, const float* __restrict__ w_sw,
    const float* __restrict__ w_out, const float* __restrict__ out_w,
    const unsigned short* __restrict__ aoT, float* __restrict__ out,
    float* __restrict__ sums)
{
  __shared__ __align__(16) short Nlds[16 * 72];
  const int lane = threadIdx.x;
  const int l15  = lane & 15;
  const int quad = lane >> 4;
  const int rid  = blockIdx.x;      // [0, 84)
  const floatx4 fzero = {0.f, 0.f, 0.f, 0.f};
  const short8* aoTv = (const short8*)aoT;

  short8 bf[2][4];
#pragma unroll
  for (int kt = 0; kt < 2; ++kt)
#pragma unroll
    for (int nt = 0; nt < 4; ++nt)
      bf[kt][nt] = aoTv[(nt * 16 + l15) * 8 + kt * 4 + quad];

  short8 af[2];
  if (rid < 48) {
    const float* wr = w_qkv + (size_t)(rid * 16 + l15) * 64;
#pragma unroll
    for (int kt = 0; kt < 2; ++kt) {
      const float* p = wr + kt * 32 + quad * 8;
      short8 f;
#pragma unroll
      for (int j = 0; j < 8; ++j) f[j] = f2bf(p[j]);
      af[kt] = f;
    }
  } else if (rid < 80) {
    int p0 = (rid - 48) * 16;
#pragma unroll
    for (int kt = 0; kt < 2; ++kt) {
      short8 f;
#pragma unroll
      for (int j = 0; j < 8; ++j) {
        int a = kt * 32 + quad * 8 + j;
        f[j] = f2bf(w_sw[a * 512 + p0 + l15]);
      }
      af[kt] = f;
    }
  } else {
    const float* wr = w_out + (size_t)((rid - 80) * 16 + l15) * 64;
#pragma unroll
    for (int kt = 0; kt < 2; ++kt) {
      const float* p = wr + kt * 32 + quad * 8;
      short8 f;
#pragma unroll
      for (int j = 0; j < 8; ++j) f[j] = f2bf(p[j]);
      af[kt] = f;
    }
  }

  floatx4 acc[4];
#pragma unroll
  for (int nt = 0; nt < 4; ++nt) acc[nt] = fzero;
#pragma unroll
  for (int kt = 0; kt < 2; ++kt)
#pragma unroll
    for (int nt = 0; nt < 4; ++nt)
      acc[nt] = MFMA_BF16(af[kt], bf[kt][nt], acc[nt], 0, 0, 0);
#pragma unroll
  for (int nt = 0; nt < 4; ++nt)
#pragma unroll
    for (int r = 0; r < 4; ++r)
      Nlds[(quad * 4 + r) * 72 + nt * 16 + l15] = f2bf(silu_f(acc[nt][r]));
  __syncthreads();

  float s1 = 0.f, s2 = 0.f;
  int matrix;

  if (rid < 48 || rid >= 80) {
    matrix = (rid < 48) ? 0 : 2;
    short8 a2[2];
#pragma unroll
    for (int kt = 0; kt < 2; ++kt)
      a2[kt] = *(const short8*)&Nlds[l15 * 72 + kt * 32 + quad * 8];
    short8 b2[2][4];
#pragma unroll
    for (int nt = 0; nt < 4; ++nt) {
      const float* wr = out_w + (size_t)(nt * 16 + l15) * 64;
#pragma unroll
      for (int kt = 0; kt < 2; ++kt) {
        const float* p = wr + kt * 32 + quad * 8;
        short8 f;
#pragma unroll
        for (int j = 0; j < 8; ++j) f[j] = f2bf(p[j]);
        b2[kt][nt] = f;
      }
    }
    floatx4 acc2[4];
#pragma unroll
    for (int nt = 0; nt < 4; ++nt) acc2[nt] = fzero;
#pragma unroll
    for (int kt = 0; kt < 2; ++kt)
#pragma unroll
      for (int nt = 0; nt < 4; ++nt)
        acc2[nt] = MFMA_BF16(a2[kt], b2[kt][nt], acc2[nt], 0, 0, 0);

    const float* Wsrc = (rid < 48) ? w_qkv : w_out;
    int base_row = (rid < 48) ? rid * 16 : (rid - 80) * 16;
    int off      = (rid < 48) ? OFF_QKV : OFF_WO;
#pragma unroll
    for (int nt = 0; nt < 4; ++nt)
#pragma unroll
      for (int r = 0; r < 4; ++r) {
        int row = base_row + quad * 4 + r;
        int col = nt * 16 + l15;
        float val = Wsrc[row * 64 + col] + acc2[nt][r];
        out[off + row * 64 + col] = val;
        s1 += val; s2 += val * val;
      }
  } else {
    matrix = 1;
    int p0 = (rid - 48) * 16;
    short8 b2[2];
#pragma unroll
    for (int kt = 0; kt < 2; ++kt)
      b2[kt] = *(const short8*)&Nlds[l15 * 72 + kt * 32 + quad * 8];
    short8 a2[4][2];
#pragma unroll
    for (int mt = 0; mt < 4; ++mt) {
      const float* wr = out_w + (size_t)(mt * 16 + l15) * 64;
#pragma unroll
      for (int kt = 0; kt < 2; ++kt) {
        const float* p = wr + kt * 32 + quad * 8;
        short8 f;
#pragma unroll
        for (int j = 0; j < 8; ++j) f[j] = f2bf(p[j]);
        a2[mt][kt] = f;
      }
    }
    floatx4 acc2[4];
#pragma unroll
    for (int mt = 0; mt < 4; ++mt) acc2[mt] = fzero;
#pragma unroll
    for (int mt = 0; mt < 4; ++mt)
#pragma unroll
      for (int kt = 0; kt < 2; ++kt)
        acc2[mt] = MFMA_BF16(a2[mt][kt], b2[kt], acc2[mt], 0, 0, 0);
#pragma unroll
    for (int mt = 0; mt < 4; ++mt)
#pragma unroll
      for (int r = 0; r < 4; ++r) {
        int a = mt * 16 + quad * 4 + r;
        int p = p0 + l15;
        int idx = a * 512 + p;
        float val = w_sw[idx] + acc2[mt][r];
        out[OFF_SW + idx] = val;
        s1 += val; s2 += val * val;
      }
  }

#pragma unroll
  for (int off = 32; off > 0; off >>= 1) {
    s1 += __shfl_down(s1, off);
    s2 += __shfl_down(s2, off);
  }
  if (lane == 0) {
    atomicAdd(&sums[matrix * 2],     s1);
    atomicAdd(&sums[matrix * 2 + 1], s2);
  }
}

// ============================ K4: final scale ==========================
__global__ __launch_bounds__(256) void k4_scale(
    float* __restrict__ out, const float* __restrict__ sums,
    const float* __restrict__ tao)
{
  int i = blockIdx.x * 256 + threadIdx.x;
  int matrix, idx; float N, tstd;
  if (i < 49152)      { matrix = 0; idx = OFF_QKV + i;           N = 49152.f; tstd = 0.125f;  }
  else if (i < 81920) { matrix = 1; idx = OFF_SW + (i - 49152);  N = 32768.f; tstd = 0.0625f; }
  else                { matrix = 2; idx = OFF_WO + (i - 81920);  N = 4096.f;  tstd = 0.0625f; }
  float sum = sums[matrix * 2], sumsq = sums[matrix * 2 + 1];
  float mean = sum / N;
  float var  = (sumsq - N * mean * mean) / (N - 1.f);
  float sd   = sqrtf(fmaxf(var, 0.f));
  float g    = fminf(fmaxf(fabsf(tao[matrix]), 1e-8f), 1.0f);
  out[idx] *= g * tstd / (sd + 1e-8f);
}

extern "C" void kernel_launch(void* const* d_in, const int* in_sizes, int n_in,
                              void* d_out, int out_size, void* d_ws, size_t ws_size,
                              hipStream_t stream) {
  const float* x     = (const float*)d_in[0];
  const float* y     = (const float*)d_in[1];
  const float* w_qkv = (const float*)d_in[2];
  const float* w_sw  = (const float*)d_in[3];
  const float* w_out = (const float*)d_in[4];
  const float* out_w = (const float*)d_in[5];
  const float* tao   = (const float*)d_in[6];
  float* out = (float*)d_out;
  float* ws  = (float*)d_ws;

  float* ao_copies      = ws;
  float* sums           = ws + WS_SUMS;
  unsigned int* counter = (unsigned int*)(ws + WS_SUMS + 6);
  unsigned short* aoT   = (unsigned short*)(ws + WS_AOT);

  hipMemsetAsync(d_ws, 0, (WS_SUMS + 8) * sizeof(float), stream);
  k1_main<<<dim3(NBLK1), dim3(256), 0, stream>>>(x, y, w_sw, w_out, out,
                                                 ao_copies, counter, aoT);
  k3_updates<<<dim3(84), dim3(64), 0, stream>>>(w_qkv, w_sw, w_out, out_w,
                                                aoT, out, sums);
  k4_scale<<<dim3(336), dim3(256), 0, stream>>>(out, sums, tao);
}

// Round 4
// 155.143 us; speedup vs baseline: 1.4009x; 1.4009x over previous
//
#include <hip/hip_runtime.h>
#include <cstdint>

typedef short short8 __attribute__((ext_vector_type(8)));
typedef short short4_t __attribute__((ext_vector_type(4)));
typedef float floatx4 __attribute__((ext_vector_type(4)));

#define MFMA_BF16 __builtin_amdgcn_mfma_f32_16x16x32_bf16

// round-to-nearest-even fp32 -> bf16 (bits in a short)
__device__ __forceinline__ short f2bf(float f) {
  union { float f; unsigned u; } a; a.f = f;
  unsigned r = a.u + 0x7FFFu + ((a.u >> 16) & 1u);
  return (short)(r >> 16);
}
__device__ __forceinline__ float bf2f(short s) {
  union { unsigned u; float f; } a;
  a.u = ((unsigned)(unsigned short)s) << 16;
  return a.f;
}
__device__ __forceinline__ float silu_f(float v) {
  return v / (1.0f + __expf(-v));
}

#define QDIM 256
#define DEMB 64
#define TILE_T 32
#define ITERS 2          // tokens per block = 64
#define NBLK1 1024       // 1024 blocks -> 4 blocks/CU target
#define YSTR 264         // shorts; 528 B rows
#define TSTR 40          // UVT t-stride in shorts; 80 B rows
#define HSTR 72          // shorts; 144 B rows

// output layout (floats)
#define OFF_QKV 4194304
#define OFF_SW  4243456
#define OFF_WO  4276224

// ws layout (floats): [0, 65536) ao partial copies (16); [65536,65542) sums;
// byte 262176: aoT bf16 [64 e][64 d]
#define AO_COPIES 16
#define WS_SUMS   65536
#define WS_AOT    65544   // float index; byte 262176 (16B aligned)

// ============================ K1: streaming ============================
__global__ __launch_bounds__(256, 2) void k1_main(
    const float* __restrict__ x, const float* __restrict__ y,
    const float* __restrict__ w_sw, const float* __restrict__ w_out,
    float* __restrict__ y_out, float* __restrict__ ao_copies)
{
  __shared__ __align__(16) short Ylds[TILE_T * YSTR];   // 16896 B
  __shared__ __align__(16) short UVT[128 * TSTR];       // 10240 B
  __shared__ __align__(16) short Hlds[TILE_T * HSTR];   //  4608 B

  const int tid  = threadIdx.x;
  const int lane = tid & 63;
  const int wave = tid >> 6;
  const int l15  = lane & 15;
  const int quad = lane >> 4;
  const floatx4 fzero = {0.f, 0.f, 0.f, 0.f};
  const int tok0 = blockIdx.x * (TILE_T * ITERS);

  // ---- register-resident B fragments (per-block conversion) ----
  short8 b1[2][8];
#pragma unroll
  for (int nt = 0; nt < 2; ++nt) {
    const float* wr = w_sw + (size_t)(wave * 32 + nt * 16 + l15) * QDIM;
#pragma unroll
    for (int kt = 0; kt < 8; ++kt) {
      const float* p = wr + kt * 32 + quad * 8;
      short8 f;
#pragma unroll
      for (int j = 0; j < 8; ++j) f[j] = f2bf(p[j]);
      b1[nt][kt] = f;
    }
  }
  short8 b2[2];
  {
    const float* wr = w_out + (size_t)(wave * 16 + l15) * DEMB;
#pragma unroll
    for (int kt = 0; kt < 2; ++kt) {
      const float* p = wr + kt * 32 + quad * 8;
      short8 f;
#pragma unroll
      for (int j = 0; j < 8; ++j) f[j] = f2bf(p[j]);
      b2[kt] = f;
    }
  }

  floatx4 ao_acc[4];
#pragma unroll
  for (int i = 0; i < 4; ++i) ao_acc[i] = fzero;

  for (int it = 0; it < ITERS; ++it) {
    const int tbase = tok0 + it * TILE_T;

    // ---- stage y tile: fp32 global -> bf16 Ylds (b64 stores) ----
    {
      const float4* src = (const float4*)(y + (size_t)tbase * QDIM);
#pragma unroll
      for (int rep = 0; rep < 8; ++rep) {
        int i = tid + rep * 256;
        float4 f = src[i];
        int tok = i >> 6;
        int col = (i & 63) * 4;
        short4_t p4 = { f2bf(f.x), f2bf(f.y), f2bf(f.z), f2bf(f.w) };
        *(short4_t*)&Ylds[tok * YSTR + col] = p4;
      }
    }
    __syncthreads();

    // ---- UV = Ytile @ Wsw^T ----
    floatx4 acc[2][2];
#pragma unroll
    for (int a = 0; a < 2; ++a)
#pragma unroll
      for (int b = 0; b < 2; ++b) acc[a][b] = fzero;
#pragma unroll
    for (int kt = 0; kt < 8; ++kt) {
      short8 a0 = *(const short8*)&Ylds[(l15)      * YSTR + kt * 32 + quad * 8];
      short8 a1 = *(const short8*)&Ylds[(16 + l15) * YSTR + kt * 32 + quad * 8];
      acc[0][0] = MFMA_BF16(a0, b1[0][kt], acc[0][0], 0, 0, 0);
      acc[0][1] = MFMA_BF16(a0, b1[1][kt], acc[0][1], 0, 0, 0);
      acc[1][0] = MFMA_BF16(a1, b1[0][kt], acc[1][0], 0, 0, 0);
      acc[1][1] = MFMA_BF16(a1, b1[1][kt], acc[1][1], 0, 0, 0);
    }
    // ---- writeback as bf16 UV^T[c][t]: packed b64 ----
#pragma unroll
    for (int mt = 0; mt < 2; ++mt)
#pragma unroll
      for (int nt = 0; nt < 2; ++nt) {
        short4_t p4;
#pragma unroll
        for (int r = 0; r < 4; ++r) p4[r] = f2bf(acc[mt][nt][r]);
        int c  = wave * 32 + nt * 16 + l15;
        int t0 = mt * 16 + quad * 4;
        *(short4_t*)&UVT[c * TSTR + t0] = p4;
      }
    __syncthreads();

    // ---- h = u * silu(v): thread = (d = tid&63, t0 = (tid>>6)*8) ----
    {
      int d  = tid & 63;
      int t0 = (tid >> 6) * 8;
      short8 u8 = *(const short8*)&UVT[d * TSTR + t0];
      short8 v8 = *(const short8*)&UVT[(64 + d) * TSTR + t0];
#pragma unroll
      for (int j = 0; j < 8; ++j) {
        float h = bf2f(u8[j]) * silu_f(bf2f(v8[j]));
        Hlds[(t0 + j) * HSTR + d] = f2bf(h);
      }
    }
    // ---- ao += u^T v (b128 fragment reads) ----
    {
      short8 a3 = *(const short8*)&UVT[(wave * 16 + l15) * TSTR + quad * 8];
#pragma unroll
      for (int et = 0; et < 4; ++et) {
        short8 b3 = *(const short8*)&UVT[(64 + et * 16 + l15) * TSTR + quad * 8];
        ao_acc[et] = MFMA_BF16(a3, b3, ao_acc[et], 0, 0, 0);
      }
    }
    __syncthreads();

    // ---- y_out = x + H @ Wout^T ----
#pragma unroll
    for (int mt = 0; mt < 2; ++mt) {
      floatx4 acc2 = fzero;
#pragma unroll
      for (int kt = 0; kt < 2; ++kt) {
        short8 a2 = *(const short8*)&Hlds[(mt * 16 + l15) * HSTR + kt * 32 + quad * 8];
        acc2 = MFMA_BF16(a2, b2[kt], acc2, 0, 0, 0);
      }
      int e = wave * 16 + l15;
#pragma unroll
      for (int r = 0; r < 4; ++r) {
        size_t idx = (size_t)(tbase + mt * 16 + quad * 4 + r) * DEMB + e;
        y_out[idx] = x[idx] + acc2[r];
      }
    }
    // no 4th sync: Ylds rewrite (next iter, after this iter's 3rd barrier)
    // cannot race its last read (before this iter's 2nd barrier).
  }

  // ---- flush ao partials (16 copies cut contention) ----
  float* dst = ao_copies + (blockIdx.x & (AO_COPIES - 1)) * 4096;
#pragma unroll
  for (int et = 0; et < 4; ++et)
#pragma unroll
    for (int r = 0; r < 4; ++r) {
      int d = wave * 16 + quad * 4 + r;
      int e = et * 16 + l15;
      atomicAdd(&dst[d * 64 + e], ao_acc[et][r]);
    }
}

// ================== K2: finalize ao -> bf16 aoT in ws ==================
__global__ __launch_bounds__(256) void k2_finalize(
    const float* __restrict__ ao_copies, unsigned short* __restrict__ aoT)
{
  __shared__ float aoFT[64 * 65];   // [e][d], pad 65
  __shared__ float ssPart[256];
  __shared__ float scRow[64];
  const int tid = threadIdx.x;

#pragma unroll
  for (int k = 0; k < 16; ++k) {
    int idx = k * 256 + tid;          // = d*64 + e, coalesced
    float v = 0.f;
#pragma unroll
    for (int c = 0; c < AO_COPIES; ++c) v += ao_copies[c * 4096 + idx];
    v *= (1.0f / 64.0f);              // /B * n_embd^-0.5
    int d = idx >> 6, e = idx & 63;
    aoFT[e * 65 + d] = v;
  }
  __syncthreads();
  {
    int d = tid >> 2, q = tid & 3;
    float ssp = 0.f;
#pragma unroll
    for (int e2 = 0; e2 < 16; ++e2) {
      float v = aoFT[(q * 16 + e2) * 65 + d];
      ssp += v * v;
    }
    ssPart[tid] = ssp;
  }
  __syncthreads();
  if (tid < 64) {
    float ss = ssPart[tid * 4] + ssPart[tid * 4 + 1] +
               ssPart[tid * 4 + 2] + ssPart[tid * 4 + 3];
    scRow[tid] = rsqrtf(ss * (1.0f / 64.0f) + 1.1920929e-07f);
  }
  __syncthreads();
#pragma unroll
  for (int k = 0; k < 16; ++k) {
    int j = k * 256 + tid;            // = e*64 + d
    int e = j >> 6, d = j & 63;
    aoT[j] = (unsigned short)f2bf(aoFT[e * 65 + d] * scRow[d]);
  }
}

// ============ K3: weight-update candidates via MFMA (84 waves) =========
__global__ __launch_bounds__(64) void k3_updates(
    const float* __restrict__ w_qkv, const float* __restrict__ w_sw,
    const float* __restrict__ w_out, const float* __restrict__ out_w,
    const unsigned short* __restrict__ aoT, float* __restrict__ out,
    float* __restrict__ sums)
{
  __shared__ __align__(16) short Nlds[16 * 72];
  const int lane = threadIdx.x;
  const int l15  = lane & 15;
  const int quad = lane >> 4;
  const int rid  = blockIdx.x;      // [0, 84)
  const floatx4 fzero = {0.f, 0.f, 0.f, 0.f};
  const short8* aoTv = (const short8*)aoT;

  short8 bf[2][4];
#pragma unroll
  for (int kt = 0; kt < 2; ++kt)
#pragma unroll
    for (int nt = 0; nt < 4; ++nt)
      bf[kt][nt] = aoTv[(nt * 16 + l15) * 8 + kt * 4 + quad];

  short8 af[2];
  if (rid < 48) {
    const float* wr = w_qkv + (size_t)(rid * 16 + l15) * 64;
#pragma unroll
    for (int kt = 0; kt < 2; ++kt) {
      const float* p = wr + kt * 32 + quad * 8;
      short8 f;
#pragma unroll
      for (int j = 0; j < 8; ++j) f[j] = f2bf(p[j]);
      af[kt] = f;
    }
  } else if (rid < 80) {
    int p0 = (rid - 48) * 16;
#pragma unroll
    for (int kt = 0; kt < 2; ++kt) {
      short8 f;
#pragma unroll
      for (int j = 0; j < 8; ++j) {
        int a = kt * 32 + quad * 8 + j;
        f[j] = f2bf(w_sw[a * 512 + p0 + l15]);
      }
      af[kt] = f;
    }
  } else {
    const float* wr = w_out + (size_t)((rid - 80) * 16 + l15) * 64;
#pragma unroll
    for (int kt = 0; kt < 2; ++kt) {
      const float* p = wr + kt * 32 + quad * 8;
      short8 f;
#pragma unroll
      for (int j = 0; j < 8; ++j) f[j] = f2bf(p[j]);
      af[kt] = f;
    }
  }

  floatx4 acc[4];
#pragma unroll
  for (int nt = 0; nt < 4; ++nt) acc[nt] = fzero;
#pragma unroll
  for (int kt = 0; kt < 2; ++kt)
#pragma unroll
    for (int nt = 0; nt < 4; ++nt)
      acc[nt] = MFMA_BF16(af[kt], bf[kt][nt], acc[nt], 0, 0, 0);
#pragma unroll
  for (int nt = 0; nt < 4; ++nt)
#pragma unroll
    for (int r = 0; r < 4; ++r)
      Nlds[(quad * 4 + r) * 72 + nt * 16 + l15] = f2bf(silu_f(acc[nt][r]));
  __syncthreads();

  float s1 = 0.f, s2 = 0.f;
  int matrix;

  if (rid < 48 || rid >= 80) {
    matrix = (rid < 48) ? 0 : 2;
    short8 a2[2];
#pragma unroll
    for (int kt = 0; kt < 2; ++kt)
      a2[kt] = *(const short8*)&Nlds[l15 * 72 + kt * 32 + quad * 8];
    short8 b2[2][4];
#pragma unroll
    for (int nt = 0; nt < 4; ++nt) {
      const float* wr = out_w + (size_t)(nt * 16 + l15) * 64;
#pragma unroll
      for (int kt = 0; kt < 2; ++kt) {
        const float* p = wr + kt * 32 + quad * 8;
        short8 f;
#pragma unroll
        for (int j = 0; j < 8; ++j) f[j] = f2bf(p[j]);
        b2[kt][nt] = f;
      }
    }
    floatx4 acc2[4];
#pragma unroll
    for (int nt = 0; nt < 4; ++nt) acc2[nt] = fzero;
#pragma unroll
    for (int kt = 0; kt < 2; ++kt)
#pragma unroll
      for (int nt = 0; nt < 4; ++nt)
        acc2[nt] = MFMA_BF16(a2[kt], b2[kt][nt], acc2[nt], 0, 0, 0);

    const float* Wsrc = (rid < 48) ? w_qkv : w_out;
    int base_row = (rid < 48) ? rid * 16 : (rid - 80) * 16;
    int off      = (rid < 48) ? OFF_QKV : OFF_WO;
#pragma unroll
    for (int nt = 0; nt < 4; ++nt)
#pragma unroll
      for (int r = 0; r < 4; ++r) {
        int row = base_row + quad * 4 + r;
        int col = nt * 16 + l15;
        float val = Wsrc[row * 64 + col] + acc2[nt][r];
        out[off + row * 64 + col] = val;
        s1 += val; s2 += val * val;
      }
  } else {
    matrix = 1;
    int p0 = (rid - 48) * 16;
    short8 b2[2];
#pragma unroll
    for (int kt = 0; kt < 2; ++kt)
      b2[kt] = *(const short8*)&Nlds[l15 * 72 + kt * 32 + quad * 8];
    short8 a2[4][2];
#pragma unroll
    for (int mt = 0; mt < 4; ++mt) {
      const float* wr = out_w + (size_t)(mt * 16 + l15) * 64;
#pragma unroll
      for (int kt = 0; kt < 2; ++kt) {
        const float* p = wr + kt * 32 + quad * 8;
        short8 f;
#pragma unroll
        for (int j = 0; j < 8; ++j) f[j] = f2bf(p[j]);
        a2[mt][kt] = f;
      }
    }
    floatx4 acc2[4];
#pragma unroll
    for (int mt = 0; mt < 4; ++mt) acc2[mt] = fzero;
#pragma unroll
    for (int mt = 0; mt < 4; ++mt)
#pragma unroll
      for (int kt = 0; kt < 2; ++kt)
        acc2[mt] = MFMA_BF16(a2[mt][kt], b2[kt], acc2[mt], 0, 0, 0);
#pragma unroll
    for (int mt = 0; mt < 4; ++mt)
#pragma unroll
      for (int r = 0; r < 4; ++r) {
        int a = mt * 16 + quad * 4 + r;
        int p = p0 + l15;
        int idx = a * 512 + p;
        float val = w_sw[idx] + acc2[mt][r];
        out[OFF_SW + idx] = val;
        s1 += val; s2 += val * val;
      }
  }

#pragma unroll
  for (int off = 32; off > 0; off >>= 1) {
    s1 += __shfl_down(s1, off);
    s2 += __shfl_down(s2, off);
  }
  if (lane == 0) {
    atomicAdd(&sums[matrix * 2],     s1);
    atomicAdd(&sums[matrix * 2 + 1], s2);
  }
}

// ============================ K4: final scale ==========================
__global__ __launch_bounds__(256) void k4_scale(
    float* __restrict__ out, const float* __restrict__ sums,
    const float* __restrict__ tao)
{
  int i = blockIdx.x * 256 + threadIdx.x;
  int matrix, idx; float N, tstd;
  if (i < 49152)      { matrix = 0; idx = OFF_QKV + i;           N = 49152.f; tstd = 0.125f;  }
  else if (i < 81920) { matrix = 1; idx = OFF_SW + (i - 49152);  N = 32768.f; tstd = 0.0625f; }
  else                { matrix = 2; idx = OFF_WO + (i - 81920);  N = 4096.f;  tstd = 0.0625f; }
  float sum = sums[matrix * 2], sumsq = sums[matrix * 2 + 1];
  float mean = sum / N;
  float var  = (sumsq - N * mean * mean) / (N - 1.f);
  float sd   = sqrtf(fmaxf(var, 0.f));
  float g    = fminf(fmaxf(fabsf(tao[matrix]), 1e-8f), 1.0f);
  out[idx] *= g * tstd / (sd + 1e-8f);
}

extern "C" void kernel_launch(void* const* d_in, const int* in_sizes, int n_in,
                              void* d_out, int out_size, void* d_ws, size_t ws_size,
                              hipStream_t stream) {
  const float* x     = (const float*)d_in[0];
  const float* y     = (const float*)d_in[1];
  const float* w_qkv = (const float*)d_in[2];
  const float* w_sw  = (const float*)d_in[3];
  const float* w_out = (const float*)d_in[4];
  const float* out_w = (const float*)d_in[5];
  const float* tao   = (const float*)d_in[6];
  float* out = (float*)d_out;
  float* ws  = (float*)d_ws;

  float* ao_copies    = ws;
  float* sums         = ws + WS_SUMS;
  unsigned short* aoT = (unsigned short*)(ws + WS_AOT);

  hipMemsetAsync(d_ws, 0, (WS_SUMS + 8) * sizeof(float), stream);
  k1_main<<<dim3(NBLK1), dim3(256), 0, stream>>>(x, y, w_sw, w_out, out, ao_copies);
  k2_finalize<<<dim3(1), dim3(256), 0, stream>>>(ao_copies, aoT);
  k3_updates<<<dim3(84), dim3(64), 0, stream>>>(w_qkv, w_sw, w_out, out_w,
                                                aoT, out, sums);
  k4_scale<<<dim3(336), dim3(256), 0, stream>>>(out, sums, tao);
}

// Round 5
// 142.586 us; speedup vs baseline: 1.5242x; 1.0881x over previous
//
#include <hip/hip_runtime.h>
#include <cstdint>

typedef short short8 __attribute__((ext_vector_type(8)));
typedef short short4_t __attribute__((ext_vector_type(4)));
typedef float floatx4 __attribute__((ext_vector_type(4)));

#define MFMA_BF16 __builtin_amdgcn_mfma_f32_16x16x32_bf16

// round-to-nearest-even fp32 -> bf16 (bits in a short)
__device__ __forceinline__ short f2bf(float f) {
  union { float f; unsigned u; } a; a.f = f;
  unsigned r = a.u + 0x7FFFu + ((a.u >> 16) & 1u);
  return (short)(r >> 16);
}
__device__ __forceinline__ float bf2f(short s) {
  union { unsigned u; float f; } a;
  a.u = ((unsigned)(unsigned short)s) << 16;
  return a.f;
}
__device__ __forceinline__ float silu_f(float v) {
  return v / (1.0f + __expf(-v));
}

#define QDIM 256
#define DEMB 64
#define TILE_T 32
#define ITERS 4          // tokens per block = 128
#define NBLK1 512        // 2 blocks/CU
#define YSTR 264         // shorts; 528 B rows
#define TSTR 40          // UVT t-stride in shorts; 80 B rows
#define HSTR 72          // shorts; 144 B rows

// output layout (floats)
#define OFF_QKV 4194304
#define OFF_SW  4243456
#define OFF_WO  4276224

// ws layout (floats):
//   [0, 65536)        ao partial copies (16 x 4096)
//   [65536, 65542)    sums
//   [65544, 67592)    aoT bf16 [64 e][64 d]        (4096 shorts)
//   [67592, 83976)    W1P bf16 frag-packed w_sw    (32768 shorts)
//   [83976, 86024)    W2P bf16 frag-packed w_out   (4096 shorts)
#define AO_COPIES 16
#define WS_SUMS   65536
#define WS_AOT    65544
#define WS_W1P    67592
#define WS_W2P    83976

// ================= K0: pre-pack weights to bf16 fragments ==============
// W1P[((wave*2+nt)*8+kt)*64 + lane] (short8) = w_sw[(wave*32+nt*16+l15)*256
//                                               + kt*32 + quad*8 + 0..7]
// W2P[(wave*2+kt)*64 + lane] (short8)       = w_out[(wave*16+l15)*64
//                                               + kt*32 + quad*8 + 0..7]
__global__ __launch_bounds__(256) void k0_pack(
    const float* __restrict__ w_sw, const float* __restrict__ w_out,
    short* __restrict__ W1P, short* __restrict__ W2P)
{
  int t = blockIdx.x * 256 + threadIdx.x;   // [0, 4608)
  if (t < 4096) {
    int lane = t & 63, kt = (t >> 6) & 7, ntw = t >> 9;
    int row = (ntw >> 1) * 32 + (ntw & 1) * 16 + (lane & 15);
    int col = kt * 32 + (lane >> 4) * 8;
    const float* p = w_sw + row * QDIM + col;
    short8 f;
#pragma unroll
    for (int j = 0; j < 8; ++j) f[j] = f2bf(p[j]);
    ((short8*)W1P)[t] = f;
  } else {
    int u = t - 4096;                       // [0, 512)
    int lane = u & 63, ktw = u >> 6;
    int row = (ktw >> 1) * 16 + (lane & 15);
    int col = (ktw & 1) * 32 + (lane >> 4) * 8;
    const float* p = w_out + row * DEMB + col;
    short8 f;
#pragma unroll
    for (int j = 0; j < 8; ++j) f[j] = f2bf(p[j]);
    ((short8*)W2P)[u] = f;
  }
}

// ============================ K1: streaming ============================
// 2-barrier pipelined loop; all global loads issued at region start and
// covered by the region's compute before the barrier drain.
__global__ __launch_bounds__(256, 2) void k1_main(
    const float* __restrict__ x, const float* __restrict__ y,
    const short* __restrict__ W1P, const short* __restrict__ W2P,
    float* __restrict__ y_out, float* __restrict__ ao_copies)
{
  __shared__ __align__(16) short Ylds[2][TILE_T * YSTR];  // 2 x 16896 B
  __shared__ __align__(16) short UVT[128 * TSTR];         // 10240 B
  __shared__ __align__(16) short Hlds[TILE_T * HSTR];     //  4608 B

  const int tid  = threadIdx.x;
  const int lane = tid & 63;
  const int wave = tid >> 6;
  const int l15  = lane & 15;
  const int quad = lane >> 4;
  const floatx4 fzero = {0.f, 0.f, 0.f, 0.f};
  const int tok0 = blockIdx.x * (TILE_T * ITERS);

  // ---- weight fragments: coalesced b128 loads, no conversion ----
  const short8* W1v = (const short8*)W1P;
  const short8* W2v = (const short8*)W2P;
  short8 b1[2][8];
#pragma unroll
  for (int nt = 0; nt < 2; ++nt)
#pragma unroll
    for (int kt = 0; kt < 8; ++kt)
      b1[nt][kt] = W1v[((wave * 2 + nt) * 8 + kt) * 64 + lane];
  short8 b2[2];
#pragma unroll
  for (int kt = 0; kt < 2; ++kt)
    b2[kt] = W2v[(wave * 2 + kt) * 64 + lane];

  floatx4 ao_acc[4];
#pragma unroll
  for (int i = 0; i < 4; ++i) ao_acc[i] = fzero;

  // ---- stage tile 0 (only exposed staging in the kernel) ----
  float4 yreg[8];
  {
    const float4* src = (const float4*)(y + (size_t)tok0 * QDIM);
#pragma unroll
    for (int rep = 0; rep < 8; ++rep) yreg[rep] = src[tid + rep * 256];
#pragma unroll
    for (int rep = 0; rep < 8; ++rep) {
      int i = tid + rep * 256;
      int tok = i >> 6;
      int col = (i & 63) * 4;
      float4 f = yreg[rep];
      short4_t p4 = { f2bf(f.x), f2bf(f.y), f2bf(f.z), f2bf(f.w) };
      *(short4_t*)&Ylds[0][tok * YSTR + col] = p4;
    }
  }
  float xreg[8];
  __syncthreads();   // barrier A (enter it=0)

  for (int it = 0; it < ITERS; ++it) {
    const int cur = it & 1;

    // ================= region RX =================
    // issue next y tile loads first (longest latency, covered by RX compute)
    if (it + 1 < ITERS) {
      const float4* src = (const float4*)(y + (size_t)(tok0 + (it + 1) * TILE_T) * QDIM);
#pragma unroll
      for (int rep = 0; rep < 8; ++rep) yreg[rep] = src[tid + rep * 256];
    }
    // epilogue of previous tile: y_out = x + H @ Wout^T
    if (it > 0) {
      const int tb = tok0 + (it - 1) * TILE_T;
#pragma unroll
      for (int mt = 0; mt < 2; ++mt) {
        floatx4 acc2 = fzero;
#pragma unroll
        for (int kt = 0; kt < 2; ++kt) {
          short8 a2 = *(const short8*)&Hlds[(mt * 16 + l15) * HSTR + kt * 32 + quad * 8];
          acc2 = MFMA_BF16(a2, b2[kt], acc2, 0, 0, 0);
        }
        int e = wave * 16 + l15;
#pragma unroll
        for (int r = 0; r < 4; ++r) {
          size_t idx = (size_t)(tb + mt * 16 + quad * 4 + r) * DEMB + e;
          y_out[idx] = xreg[mt * 4 + r] + acc2[r];
        }
      }
    }
    // UV = Ytile @ Wsw^T
    floatx4 acc[2][2];
#pragma unroll
    for (int a = 0; a < 2; ++a)
#pragma unroll
      for (int b = 0; b < 2; ++b) acc[a][b] = fzero;
#pragma unroll
    for (int kt = 0; kt < 8; ++kt) {
      short8 a0 = *(const short8*)&Ylds[cur][(l15)      * YSTR + kt * 32 + quad * 8];
      short8 a1 = *(const short8*)&Ylds[cur][(16 + l15) * YSTR + kt * 32 + quad * 8];
      acc[0][0] = MFMA_BF16(a0, b1[0][kt], acc[0][0], 0, 0, 0);
      acc[0][1] = MFMA_BF16(a0, b1[1][kt], acc[0][1], 0, 0, 0);
      acc[1][0] = MFMA_BF16(a1, b1[0][kt], acc[1][0], 0, 0, 0);
      acc[1][1] = MFMA_BF16(a1, b1[1][kt], acc[1][1], 0, 0, 0);
    }
    // writeback as bf16 UV^T[c][t]: packed b64
#pragma unroll
    for (int mt = 0; mt < 2; ++mt)
#pragma unroll
      for (int nt = 0; nt < 2; ++nt) {
        short4_t p4;
#pragma unroll
        for (int r = 0; r < 4; ++r) p4[r] = f2bf(acc[mt][nt][r]);
        int c  = wave * 32 + nt * 16 + l15;
        int t0 = mt * 16 + quad * 4;
        *(short4_t*)&UVT[c * TSTR + t0] = p4;
      }
    __syncthreads();   // barrier B

    // ================= region RY =================
    // issue x loads for THIS tile (used in next RX's epilogue)
    {
      const float* xb = x + (size_t)(tok0 + it * TILE_T) * DEMB + wave * 16 + l15;
#pragma unroll
      for (int mt = 0; mt < 2; ++mt)
#pragma unroll
        for (int r = 0; r < 4; ++r)
          xreg[mt * 4 + r] = xb[(mt * 16 + quad * 4 + r) * DEMB];
    }
    // h = u * silu(v) -> Hlds
    {
      int d  = tid & 63;
      int t0 = (tid >> 6) * 8;
      short8 u8 = *(const short8*)&UVT[d * TSTR + t0];
      short8 v8 = *(const short8*)&UVT[(64 + d) * TSTR + t0];
#pragma unroll
      for (int j = 0; j < 8; ++j) {
        float h = bf2f(u8[j]) * silu_f(bf2f(v8[j]));
        Hlds[(t0 + j) * HSTR + d] = f2bf(h);
      }
    }
    // ao += u^T v
    {
      short8 a3 = *(const short8*)&UVT[(wave * 16 + l15) * TSTR + quad * 8];
#pragma unroll
      for (int et = 0; et < 4; ++et) {
        short8 b3 = *(const short8*)&UVT[(64 + et * 16 + l15) * TSTR + quad * 8];
        ao_acc[et] = MFMA_BF16(a3, b3, ao_acc[et], 0, 0, 0);
      }
    }
    // pack prefetched y -> other Y buffer
    if (it + 1 < ITERS) {
#pragma unroll
      for (int rep = 0; rep < 8; ++rep) {
        int i = tid + rep * 256;
        int tok = i >> 6;
        int col = (i & 63) * 4;
        float4 f = yreg[rep];
        short4_t p4 = { f2bf(f.x), f2bf(f.y), f2bf(f.z), f2bf(f.w) };
        *(short4_t*)&Ylds[1 - cur][tok * YSTR + col] = p4;
      }
    }
    __syncthreads();   // barrier A (next iter)
  }

  // ---- final epilogue (tile ITERS-1) ----
  {
    const int tb = tok0 + (ITERS - 1) * TILE_T;
#pragma unroll
    for (int mt = 0; mt < 2; ++mt) {
      floatx4 acc2 = fzero;
#pragma unroll
      for (int kt = 0; kt < 2; ++kt) {
        short8 a2 = *(const short8*)&Hlds[(mt * 16 + l15) * HSTR + kt * 32 + quad * 8];
        acc2 = MFMA_BF16(a2, b2[kt], acc2, 0, 0, 0);
      }
      int e = wave * 16 + l15;
#pragma unroll
      for (int r = 0; r < 4; ++r) {
        size_t idx = (size_t)(tb + mt * 16 + quad * 4 + r) * DEMB + e;
        y_out[idx] = xreg[mt * 4 + r] + acc2[r];
      }
    }
  }

  // ---- flush ao partials ----
  float* dst = ao_copies + (blockIdx.x & (AO_COPIES - 1)) * 4096;
#pragma unroll
  for (int et = 0; et < 4; ++et)
#pragma unroll
    for (int r = 0; r < 4; ++r) {
      int d = wave * 16 + quad * 4 + r;
      int e = et * 16 + l15;
      atomicAdd(&dst[d * 64 + e], ao_acc[et][r]);
    }
}

// ================== K2: finalize ao -> bf16 aoT in ws ==================
__global__ __launch_bounds__(256) void k2_finalize(
    const float* __restrict__ ao_copies, unsigned short* __restrict__ aoT)
{
  __shared__ float aoFT[64 * 65];   // [e][d], pad 65
  __shared__ float ssPart[256];
  __shared__ float scRow[64];
  const int tid = threadIdx.x;

#pragma unroll
  for (int k = 0; k < 16; ++k) {
    int idx = k * 256 + tid;          // = d*64 + e, coalesced
    float v = 0.f;
#pragma unroll
    for (int c = 0; c < AO_COPIES; ++c) v += ao_copies[c * 4096 + idx];
    v *= (1.0f / 64.0f);              // /B * n_embd^-0.5
    int d = idx >> 6, e = idx & 63;
    aoFT[e * 65 + d] = v;
  }
  __syncthreads();
  {
    int d = tid >> 2, q = tid & 3;
    float ssp = 0.f;
#pragma unroll
    for (int e2 = 0; e2 < 16; ++e2) {
      float v = aoFT[(q * 16 + e2) * 65 + d];
      ssp += v * v;
    }
    ssPart[tid] = ssp;
  }
  __syncthreads();
  if (tid < 64) {
    float ss = ssPart[tid * 4] + ssPart[tid * 4 + 1] +
               ssPart[tid * 4 + 2] + ssPart[tid * 4 + 3];
    scRow[tid] = rsqrtf(ss * (1.0f / 64.0f) + 1.1920929e-07f);
  }
  __syncthreads();
#pragma unroll
  for (int k = 0; k < 16; ++k) {
    int j = k * 256 + tid;            // = e*64 + d
    int e = j >> 6, d = j & 63;
    aoT[j] = (unsigned short)f2bf(aoFT[e * 65 + d] * scRow[d]);
  }
}

// ============ K3: weight-update candidates via MFMA (84 waves) =========
__global__ __launch_bounds__(64) void k3_updates(
    const float* __restrict__ w_qkv, const float* __restrict__ w_sw,
    const float* __restrict__ w_out, const float* __restrict__ out_w,
    const unsigned short* __restrict__ aoT, float* __restrict__ out,
    float* __restrict__ sums)
{
  __shared__ __align__(16) short Nlds[16 * 72];
  const int lane = threadIdx.x;
  const int l15  = lane & 15;
  const int quad = lane >> 4;
  const int rid  = blockIdx.x;      // [0, 84)
  const floatx4 fzero = {0.f, 0.f, 0.f, 0.f};
  const short8* aoTv = (const short8*)aoT;

  short8 bf[2][4];
#pragma unroll
  for (int kt = 0; kt < 2; ++kt)
#pragma unroll
    for (int nt = 0; nt < 4; ++nt)
      bf[kt][nt] = aoTv[(nt * 16 + l15) * 8 + kt * 4 + quad];

  short8 af[2];
  if (rid < 48) {
    const float* wr = w_qkv + (size_t)(rid * 16 + l15) * 64;
#pragma unroll
    for (int kt = 0; kt < 2; ++kt) {
      const float* p = wr + kt * 32 + quad * 8;
      short8 f;
#pragma unroll
      for (int j = 0; j < 8; ++j) f[j] = f2bf(p[j]);
      af[kt] = f;
    }
  } else if (rid < 80) {
    int p0 = (rid - 48) * 16;
#pragma unroll
    for (int kt = 0; kt < 2; ++kt) {
      short8 f;
#pragma unroll
      for (int j = 0; j < 8; ++j) {
        int a = kt * 32 + quad * 8 + j;
        f[j] = f2bf(w_sw[a * 512 + p0 + l15]);
      }
      af[kt] = f;
    }
  } else {
    const float* wr = w_out + (size_t)((rid - 80) * 16 + l15) * 64;
#pragma unroll
    for (int kt = 0; kt < 2; ++kt) {
      const float* p = wr + kt * 32 + quad * 8;
      short8 f;
#pragma unroll
      for (int j = 0; j < 8; ++j) f[j] = f2bf(p[j]);
      af[kt] = f;
    }
  }

  floatx4 acc[4];
#pragma unroll
  for (int nt = 0; nt < 4; ++nt) acc[nt] = fzero;
#pragma unroll
  for (int kt = 0; kt < 2; ++kt)
#pragma unroll
    for (int nt = 0; nt < 4; ++nt)
      acc[nt] = MFMA_BF16(af[kt], bf[kt][nt], acc[nt], 0, 0, 0);
#pragma unroll
  for (int nt = 0; nt < 4; ++nt)
#pragma unroll
    for (int r = 0; r < 4; ++r)
      Nlds[(quad * 4 + r) * 72 + nt * 16 + l15] = f2bf(silu_f(acc[nt][r]));
  __syncthreads();

  float s1 = 0.f, s2 = 0.f;
  int matrix;

  if (rid < 48 || rid >= 80) {
    matrix = (rid < 48) ? 0 : 2;
    short8 a2[2];
#pragma unroll
    for (int kt = 0; kt < 2; ++kt)
      a2[kt] = *(const short8*)&Nlds[l15 * 72 + kt * 32 + quad * 8];
    short8 b2[2][4];
#pragma unroll
    for (int nt = 0; nt < 4; ++nt) {
      const float* wr = out_w + (size_t)(nt * 16 + l15) * 64;
#pragma unroll
      for (int kt = 0; kt < 2; ++kt) {
        const float* p = wr + kt * 32 + quad * 8;
        short8 f;
#pragma unroll
        for (int j = 0; j < 8; ++j) f[j] = f2bf(p[j]);
        b2[kt][nt] = f;
      }
    }
    floatx4 acc2[4];
#pragma unroll
    for (int nt = 0; nt < 4; ++nt) acc2[nt] = fzero;
#pragma unroll
    for (int kt = 0; kt < 2; ++kt)
#pragma unroll
      for (int nt = 0; nt < 4; ++nt)
        acc2[nt] = MFMA_BF16(a2[kt], b2[kt][nt], acc2[nt], 0, 0, 0);

    const float* Wsrc = (rid < 48) ? w_qkv : w_out;
    int base_row = (rid < 48) ? rid * 16 : (rid - 80) * 16;
    int off      = (rid < 48) ? OFF_QKV : OFF_WO;
#pragma unroll
    for (int nt = 0; nt < 4; ++nt)
#pragma unroll
      for (int r = 0; r < 4; ++r) {
        int row = base_row + quad * 4 + r;
        int col = nt * 16 + l15;
        float val = Wsrc[row * 64 + col] + acc2[nt][r];
        out[off + row * 64 + col] = val;
        s1 += val; s2 += val * val;
      }
  } else {
    matrix = 1;
    int p0 = (rid - 48) * 16;
    short8 b2[2];
#pragma unroll
    for (int kt = 0; kt < 2; ++kt)
      b2[kt] = *(const short8*)&Nlds[l15 * 72 + kt * 32 + quad * 8];
    short8 a2[4][2];
#pragma unroll
    for (int mt = 0; mt < 4; ++mt) {
      const float* wr = out_w + (size_t)(mt * 16 + l15) * 64;
#pragma unroll
      for (int kt = 0; kt < 2; ++kt) {
        const float* p = wr + kt * 32 + quad * 8;
        short8 f;
#pragma unroll
        for (int j = 0; j < 8; ++j) f[j] = f2bf(p[j]);
        a2[mt][kt] = f;
      }
    }
    floatx4 acc2[4];
#pragma unroll
    for (int mt = 0; mt < 4; ++mt) acc2[mt] = fzero;
#pragma unroll
    for (int mt = 0; mt < 4; ++mt)
#pragma unroll
      for (int kt = 0; kt < 2; ++kt)
        acc2[mt] = MFMA_BF16(a2[mt][kt], b2[kt], acc2[mt], 0, 0, 0);
#pragma unroll
    for (int mt = 0; mt < 4; ++mt)
#pragma unroll
      for (int r = 0; r < 4; ++r) {
        int a = mt * 16 + quad * 4 + r;
        int p = p0 + l15;
        int idx = a * 512 + p;
        float val = w_sw[idx] + acc2[mt][r];
        out[OFF_SW + idx] = val;
        s1 += val; s2 += val * val;
      }
  }

#pragma unroll
  for (int off = 32; off > 0; off >>= 1) {
    s1 += __shfl_down(s1, off);
    s2 += __shfl_down(s2, off);
  }
  if (lane == 0) {
    atomicAdd(&sums[matrix * 2],     s1);
    atomicAdd(&sums[matrix * 2 + 1], s2);
  }
}

// ============================ K4: final scale ==========================
__global__ __launch_bounds__(256) void k4_scale(
    float* __restrict__ out, const float* __restrict__ sums,
    const float* __restrict__ tao)
{
  int i = blockIdx.x * 256 + threadIdx.x;
  int matrix, idx; float N, tstd;
  if (i < 49152)      { matrix = 0; idx = OFF_QKV + i;           N = 49152.f; tstd = 0.125f;  }
  else if (i < 81920) { matrix = 1; idx = OFF_SW + (i - 49152);  N = 32768.f; tstd = 0.0625f; }
  else                { matrix = 2; idx = OFF_WO + (i - 81920);  N = 4096.f;  tstd = 0.0625f; }
  float sum = sums[matrix * 2], sumsq = sums[matrix * 2 + 1];
  float mean = sum / N;
  float var  = (sumsq - N * mean * mean) / (N - 1.f);
  float sd   = sqrtf(fmaxf(var, 0.f));
  float g    = fminf(fmaxf(fabsf(tao[matrix]), 1e-8f), 1.0f);
  out[idx] *= g * tstd / (sd + 1e-8f);
}

extern "C" void kernel_launch(void* const* d_in, const int* in_sizes, int n_in,
                              void* d_out, int out_size, void* d_ws, size_t ws_size,
                              hipStream_t stream) {
  const float* x     = (const float*)d_in[0];
  const float* y     = (const float*)d_in[1];
  const float* w_qkv = (const float*)d_in[2];
  const float* w_sw  = (const float*)d_in[3];
  const float* w_out = (const float*)d_in[4];
  const float* out_w = (const float*)d_in[5];
  const float* tao   = (const float*)d_in[6];
  float* out = (float*)d_out;
  float* ws  = (float*)d_ws;

  float* ao_copies    = ws;
  float* sums         = ws + WS_SUMS;
  unsigned short* aoT = (unsigned short*)(ws + WS_AOT);
  short* W1P          = (short*)(ws + WS_W1P);
  short* W2P          = (short*)(ws + WS_W2P);

  hipMemsetAsync(d_ws, 0, (WS_SUMS + 8) * sizeof(float), stream);
  k0_pack<<<dim3(18), dim3(256), 0, stream>>>(w_sw, w_out, W1P, W2P);
  k1_main<<<dim3(NBLK1), dim3(256), 0, stream>>>(x, y, W1P, W2P, out, ao_copies);
  k2_finalize<<<dim3(1), dim3(256), 0, stream>>>(ao_copies, aoT);
  k3_updates<<<dim3(84), dim3(64), 0, stream>>>(w_qkv, w_sw, w_out, out_w,
                                                aoT, out, sums);
  k4_scale<<<dim3(336), dim3(256), 0, stream>>>(out, sums, tao);
}